// Round 12
// baseline (1571.509 us; speedup 1.0000x reference)
//
#include <hip/hip_runtime.h>
#include <math.h>

#define D 128
#define NSTATE 16
#define DR 8
#define T_SEQ 1024
#define NTOK 131072  // 128 sequences * 1024 tokens
#define SEG 8        // segments per sequence (parallel scan)
#define SEGLEN 128   // T_SEQ / SEG
#define CH 16        // chunk (timesteps staged in LDS at once)
#define ZS 136       // bf16 elems per z row (128 + 8 pad -> 272B stride)
#define XRS2 132     // f32 elems per xr row (128 + 4 pad) — conv half only

typedef __attribute__((ext_vector_type(8))) short bf16x8;
typedef __attribute__((ext_vector_type(4))) float f32x4;

#define LOG2E 1.44269504088896340736f
#define LN2   0.69314718055994530942f

// fast sigmoid: 1/(1+2^(-x*log2e)) via v_exp + v_rcp (~1 ulp)
__device__ __forceinline__ float sigmoidf_(float x) {
    return __builtin_amdgcn_rcpf(1.0f + exp2f(-x * LOG2E));
}
// fast softplus: ln2 * log2(1 + 2^(x*log2e)) via v_exp + v_log
__device__ __forceinline__ float softplusf_(float x) {
    float t = LN2 * __builtin_amdgcn_logf(1.0f + exp2f(x * LOG2E));
    return (x > 20.0f) ? x : t;
}
__device__ __forceinline__ short f2bf(float f) {   // RNE float->bf16
    union { float f; unsigned u; } v; v.f = f;
    unsigned r = v.u + 0x7FFFu + ((v.u >> 16) & 1u);
    return (short)(r >> 16);
}
__device__ __forceinline__ float bf2f(short s) {
    union { unsigned u; float f; } v; v.u = ((unsigned)(unsigned short)s) << 16;
    return v.f;
}

// ---------------- prep kernels ----------------

// f32 -> bf16 hi/lo split, elementwise (layout preserved)
__global__ void k_prepw(const float* __restrict__ src, short* __restrict__ hi,
                        short* __restrict__ lo, int n) {
    int i = blockIdx.x * 256 + threadIdx.x;
    if (i < n) {
        float f = src[i];
        short hh = f2bf(f);
        hi[i] = hh;
        lo[i] = f2bf(f - bf2f(hh));
    }
}

// xp_w (L,40,128) -> padded (L,48,128) bf16 hi/lo, rows 40..47 zero
__global__ void k_prepw_xp(const float* __restrict__ src, short* __restrict__ hi,
                           short* __restrict__ lo) {
    int i = blockIdx.x * 256 + threadIdx.x;     // over 4*48*128
    if (i >= 4 * 48 * 128) return;
    int l = i / (48 * 128);
    int rem = i - l * 48 * 128;
    int j = rem >> 7, k = rem & 127;
    float f = (j < 40) ? src[(l * 40 + j) * 128 + k] : 0.f;
    short hh = f2bf(f);
    hi[i] = hh;
    lo[i] = f2bf(f - bf2f(hh));
}

// A2 = -exp(A_log) * log2(e)
__global__ void k_a2(const float* __restrict__ A_log, float* __restrict__ A2, int total) {
    int idx = blockIdx.x * blockDim.x + threadIdx.x;
    if (idx < total) A2[idx] = -__expf(A_log[idx]) * LOG2E;
}

// h[tok][d] = x[tok] * inp_w[d] + inp_b[d]
__global__ void k_init_h(const float* __restrict__ x, const float* __restrict__ inp_w,
                         const float* __restrict__ inp_b, float* __restrict__ h) {
    int idx = blockIdx.x * blockDim.x + threadIdx.x;
    int tok = idx >> 7;
    int d = idx & 127;
    h[idx] = x[tok] * inp_w[d] + inp_b[d];
}

// ---------------- per-layer kernels ----------------
// Fused LN + in_proj (3-term split-bf16 MFMA) + causal conv(k=3) + SiLU
// + x_proj (second MFMA stage on the xc tile) -> xc, res, bc, dlt.
__global__ __launch_bounds__(256) void k_ln_inproj_conv(
    const float* __restrict__ h, const float* __restrict__ ln_g, const float* __restrict__ ln_b,
    const short* __restrict__ wh, const short* __restrict__ wl,   // in_proj (256,128) hi/lo
    const short* __restrict__ xph, const short* __restrict__ xpl, // x_proj padded (48,128) hi/lo
    const float* __restrict__ conv_w, const float* __restrict__ conv_b,
    float* __restrict__ xc, float* __restrict__ res,
    float* __restrict__ bc, float* __restrict__ dlt)
{
    __shared__ __align__(16) short zsh[48 * ZS];
    __shared__ __align__(16) short zsl[48 * ZS];
    __shared__ __align__(16) float xr[34 * XRS2];
    const int tid = threadIdx.x;
    const int wv = tid >> 6, lane = tid & 63;
    const int tstart = blockIdx.x * 32;
    const int tin = tstart & (T_SEQ - 1);

    // Phase A: LayerNorm rows 0..33 -> bf16 hi/lo
    for (int r = wv; r < 34; r += 4) {
        int tr = tin + r - 2;
        if (tr < 0) {
            zsh[r * ZS + lane] = 0; zsh[r * ZS + lane + 64] = 0;
            zsl[r * ZS + lane] = 0; zsl[r * ZS + lane + 64] = 0;
            continue;
        }
        size_t row = (size_t)(tstart + r - 2) * D;
        float a = h[row + lane];
        float b = h[row + lane + 64];
        float s = a + b, ss = a * a + b * b;
        #pragma unroll
        for (int m = 1; m < 64; m <<= 1) { s += __shfl_xor(s, m); ss += __shfl_xor(ss, m); }
        float mu = s * (1.0f / 128.0f);
        float var = ss * (1.0f / 128.0f) - mu * mu;
        float rstd = rsqrtf(var + 1e-5f);
        float z0 = (a - mu) * rstd * ln_g[lane]      + ln_b[lane];
        float z1 = (b - mu) * rstd * ln_g[lane + 64] + ln_b[lane + 64];
        short h0 = f2bf(z0), h1 = f2bf(z1);
        zsh[r * ZS + lane]      = h0;
        zsh[r * ZS + lane + 64] = h1;
        zsl[r * ZS + lane]      = f2bf(z0 - bf2f(h0));
        zsl[r * ZS + lane + 64] = f2bf(z1 - bf2f(h1));
    }
    for (int i = tid; i < 14 * 128; i += 256) {
        int r = 34 + (i >> 7), c = i & 127;
        zsh[r * ZS + c] = 0;
        zsl[r * ZS + c] = 0;
    }

    // B panel (hi) -> registers
    const int colb = wv * 64 + (lane & 15);
    const int kb = (lane >> 4) * 8;
    bf16x8 bw[4][4];
    #pragma unroll
    for (int ct = 0; ct < 4; ++ct)
        #pragma unroll
        for (int kf = 0; kf < 4; ++kf)
            bw[ct][kf] = *(const bf16x8*)&wh[(colb + ct * 16) * 128 + kf * 32 + kb];
    __syncthreads();

    f32x4 acc[3][4];
    #pragma unroll
    for (int b = 0; b < 3; ++b)
        #pragma unroll
        for (int ct = 0; ct < 4; ++ct)
            acc[b][ct] = (f32x4){0.f, 0.f, 0.f, 0.f};

    // Pass 1: (a_hi + a_lo) * b_hi
    #pragma unroll
    for (int b = 0; b < 3; ++b) {
        bf16x8 ah[4], al[4];
        const int rbase = (b * 16 + (lane & 15)) * ZS + kb;
        #pragma unroll
        for (int kf = 0; kf < 4; ++kf) {
            ah[kf] = *(const bf16x8*)&zsh[rbase + kf * 32];
            al[kf] = *(const bf16x8*)&zsl[rbase + kf * 32];
        }
        #pragma unroll
        for (int ct = 0; ct < 4; ++ct)
            #pragma unroll
            for (int kf = 0; kf < 4; ++kf) {
                acc[b][ct] = __builtin_amdgcn_mfma_f32_16x16x32_bf16(ah[kf], bw[ct][kf], acc[b][ct], 0, 0, 0);
                acc[b][ct] = __builtin_amdgcn_mfma_f32_16x16x32_bf16(al[kf], bw[ct][kf], acc[b][ct], 0, 0, 0);
            }
    }
    // Pass 2: a_hi * b_lo
    #pragma unroll
    for (int ct = 0; ct < 4; ++ct)
        #pragma unroll
        for (int kf = 0; kf < 4; ++kf)
            bw[ct][kf] = *(const bf16x8*)&wl[(colb + ct * 16) * 128 + kf * 32 + kb];
    #pragma unroll
    for (int b = 0; b < 3; ++b) {
        bf16x8 ah[4];
        const int rbase = (b * 16 + (lane & 15)) * ZS + kb;
        #pragma unroll
        for (int kf = 0; kf < 4; ++kf)
            ah[kf] = *(const bf16x8*)&zsh[rbase + kf * 32];
        #pragma unroll
        for (int ct = 0; ct < 4; ++ct)
            #pragma unroll
            for (int kf = 0; kf < 4; ++kf)
                acc[b][ct] = __builtin_amdgcn_mfma_f32_16x16x32_bf16(ah[kf], bw[ct][kf], acc[b][ct], 0, 0, 0);
    }

    // acc -> xr (conv half, waves 0-1) or direct global res (gate half, waves 2-3)
    if (wv < 2) {
        #pragma unroll
        for (int b = 0; b < 3; ++b)
            #pragma unroll
            for (int ct = 0; ct < 4; ++ct) {
                const int col = wv * 64 + ct * 16 + (lane & 15);
                #pragma unroll
                for (int i = 0; i < 4; ++i) {
                    int row = b * 16 + ((lane >> 4) << 2) + i;
                    if (row < 34) xr[row * XRS2 + col] = acc[b][ct][i];
                }
            }
    } else {
        #pragma unroll
        for (int b = 0; b < 3; ++b)
            #pragma unroll
            for (int ct = 0; ct < 4; ++ct) {
                const int col = (wv - 2) * 64 + ct * 16 + (lane & 15);  // 0..127 of gate
                #pragma unroll
                for (int i = 0; i < 4; ++i) {
                    int row = b * 16 + ((lane >> 4) << 2) + i;
                    if (row >= 2 && row < 34)
                        res[(size_t)(tstart + row - 2) * D + col] = acc[b][ct][i];
                }
            }
    }
    __syncthreads();

    // Epilogue: conv+silu -> xc (global + LDS bf16 split into zsh/zsl rows 0..31)
    if (tid < 128) {
        float c0 = conv_w[tid * 3 + 0], c1 = conv_w[tid * 3 + 1], c2 = conv_w[tid * 3 + 2];
        float cb = conv_b[tid];
        float v0 = xr[0 * XRS2 + tid], v1 = xr[1 * XRS2 + tid];
        #pragma unroll
        for (int s = 0; s < 32; ++s) {
            float v2 = xr[(s + 2) * XRS2 + tid];
            float v = v0 * c0 + v1 * c1 + v2 * c2 + cb;
            v = v * sigmoidf_(v);
            xc[(size_t)(tstart + s) * D + tid] = v;
            short hh = f2bf(v);
            zsh[s * ZS + tid] = hh;
            zsl[s * ZS + tid] = f2bf(v - bf2f(hh));
            v0 = v1; v1 = v2;
        }
    }
    __syncthreads();

    // Stage 2 MFMA: dbc = xc @ xp_w.T  (M=32, N=48 padded, K=128), 3-term split.
    for (int tile = wv; tile < 6; tile += 4) {
        const int b = tile & 1, ct = tile >> 1;
        const int jcol = ct * 16 + (lane & 15);
        const int rbase = (b * 16 + (lane & 15)) * ZS + kb;
        bf16x8 ah[4], al[4], bh[4];
        #pragma unroll
        for (int kf = 0; kf < 4; ++kf) {
            ah[kf] = *(const bf16x8*)&zsh[rbase + kf * 32];
            al[kf] = *(const bf16x8*)&zsl[rbase + kf * 32];
            bh[kf] = *(const bf16x8*)&xph[jcol * 128 + kf * 32 + kb];
        }
        f32x4 a2 = (f32x4){0.f, 0.f, 0.f, 0.f};
        #pragma unroll
        for (int kf = 0; kf < 4; ++kf) {
            a2 = __builtin_amdgcn_mfma_f32_16x16x32_bf16(ah[kf], bh[kf], a2, 0, 0, 0);
            a2 = __builtin_amdgcn_mfma_f32_16x16x32_bf16(al[kf], bh[kf], a2, 0, 0, 0);
        }
        #pragma unroll
        for (int kf = 0; kf < 4; ++kf) {
            bh[kf] = *(const bf16x8*)&xpl[jcol * 128 + kf * 32 + kb];
            a2 = __builtin_amdgcn_mfma_f32_16x16x32_bf16(ah[kf], bh[kf], a2, 0, 0, 0);
        }
        #pragma unroll
        for (int i = 0; i < 4; ++i) {
            int tok = tstart + b * 16 + ((lane >> 4) << 2) + i;
            if (jcol < 8)
                dlt[(size_t)tok * 8 + jcol] = a2[i];
            else if (jcol < 40)
                bc[(size_t)tok * 32 + (jcol - 8)] = a2[i];
        }
    }
}

// ---- chunk-parallel selective scan, linear-correction form ----
// Pass A: per-segment scan from x=0, emitting y_local = C.x_local + u*Dp
// (written IN-PLACE over xc), F (final state), P = exp2(A2*sum dt).
// Grid 128x8x2 = 2048 blocks x 256 threads (64 d x 4 n-quads).
__global__ __launch_bounds__(256) void k_scanA(
    float* __restrict__ xcy,             // in: u, out: y_local
    const float* __restrict__ bc, const float* __restrict__ dlt,
    const float* __restrict__ dp_w, const float* __restrict__ dp_b,
    const float* __restrict__ A2, const float* __restrict__ Dp,
    float* __restrict__ Pbuf, float* __restrict__ Fbuf)
{
    __shared__ float u_l[CH][64];
    __shared__ float bc_l[CH][32];
    __shared__ float dlt_l[CH][8];
    __shared__ float dl_l[CH][64];
    __shared__ float dpw_s[64][9];
    __shared__ float dpb_s[64];

    const int tid = threadIdx.x;
    const int bt = blockIdx.x >> 4;
    const int seg = (blockIdx.x >> 1) & 7;
    const int d0 = (blockIdx.x & 1) * 64;
    const int dd = tid >> 2, q = tid & 3;
    const int d = d0 + dd;

    #pragma unroll
    for (int i = 0; i < 2; ++i) {
        int idx = tid + i * 256;
        dpw_s[idx >> 3][idx & 7] = dp_w[(d0 + (idx >> 3)) * 8 + (idx & 7)];
    }
    if (tid < 64) dpb_s[tid] = dp_b[d0 + tid];
    float A2q[4];
    #pragma unroll
    for (int jn = 0; jn < 4; ++jn) A2q[jn] = A2[d * NSTATE + q * 4 + jn];
    const float Dpd = Dp[d];
    float x0 = 0.f, x1 = 0.f, x2 = 0.f, x3 = 0.f, S = 0.f;

    const size_t segbase = (size_t)bt * T_SEQ + (size_t)seg * SEGLEN;
    float4 su, sbc, sdl;
    su = *(const float4*)&xcy[(segbase + (tid >> 4)) * D + d0 + (tid & 15) * 4];
    if (tid < 128) sbc = *(const float4*)&bc[(segbase + (tid >> 3)) * 32 + (tid & 7) * 4];
    if (tid < 32)  sdl = *(const float4*)&dlt[(segbase + (tid >> 1)) * 8 + (tid & 1) * 4];

    for (int c = 0; c < SEGLEN / CH; ++c) {
        const size_t tb = segbase + (size_t)c * CH;
        *(float4*)&u_l[tid >> 4][(tid & 15) * 4] = su;
        if (tid < 128) *(float4*)&bc_l[tid >> 3][(tid & 7) * 4] = sbc;
        if (tid < 32)  *(float4*)&dlt_l[tid >> 1][(tid & 1) * 4] = sdl;
        __syncthreads();
        if (c + 1 < SEGLEN / CH) {
            const size_t nb = tb + CH;
            su = *(const float4*)&xcy[(nb + (tid >> 4)) * D + d0 + (tid & 15) * 4];
            if (tid < 128) sbc = *(const float4*)&bc[(nb + (tid >> 3)) * 32 + (tid & 7) * 4];
            if (tid < 32)  sdl = *(const float4*)&dlt[(nb + (tid >> 1)) * 8 + (tid & 1) * 4];
        }
        {
            int col = tid & 63;
            #pragma unroll
            for (int i = 0; i < 4; ++i) {
                int row = (tid >> 6) + 4 * i;
                float v = dpb_s[col];
                #pragma unroll
                for (int r = 0; r < DR; ++r) v = fmaf(dlt_l[row][r], dpw_s[col][r], v);
                dl_l[row][col] = softplusf_(v);
            }
        }
        __syncthreads();
        float pacc[CH];
        #pragma unroll
        for (int tl = 0; tl < CH; ++tl) {
            float dt = dl_l[tl][dd];
            float uv = u_l[tl][dd];
            float duv = dt * uv;
            S += dt;
            float4 Bq = *(const float4*)&bc_l[tl][q * 4];
            float4 Cq = *(const float4*)&bc_l[tl][16 + q * 4];
            x0 = fmaf(exp2f(dt * A2q[0]), x0, duv * Bq.x);
            x1 = fmaf(exp2f(dt * A2q[1]), x1, duv * Bq.y);
            x2 = fmaf(exp2f(dt * A2q[2]), x2, duv * Bq.z);
            x3 = fmaf(exp2f(dt * A2q[3]), x3, duv * Bq.w);
            float p = x0 * Cq.x;
            p = fmaf(x1, Cq.y, p);
            p = fmaf(x2, Cq.z, p);
            p = fmaf(x3, Cq.w, p);
            p += __shfl_xor(p, 1);
            p += __shfl_xor(p, 2);
            pacc[tl] = fmaf(uv, Dpd, p);
        }
        if (q == 0) {
            #pragma unroll
            for (int tl = 0; tl < CH; ++tl)
                xcy[(tb + tl) * D + d] = pacc[tl];   // y_local (ungated)
        }
        __syncthreads();
    }
    const size_t o = ((size_t)(bt * SEG + seg) * D + d) * NSTATE + q * 4;
    *(float4*)&Fbuf[o] = make_float4(x0, x1, x2, x3);
    *(float4*)&Pbuf[o] = make_float4(exp2f(A2q[0] * S), exp2f(A2q[1] * S),
                                     exp2f(A2q[2] * S), exp2f(A2q[3] * S));
}

// Pass B: inline fix-up -> x_init, then PARALLEL correction:
// y_t = y_local_t + sum_n exp2(A2[n]*S_t)*x_init[n]*C_t[n], gated, -> resy.
// S_t recomputed from dlt (identical code path => identical dt values).
// No cross-step state chain: only a scalar prefix add carries.
__global__ __launch_bounds__(256) void k_scanB(
    const float* __restrict__ ylocal,    // = xc (y_local from pass A)
    const float* __restrict__ bc, const float* __restrict__ dlt,
    const float* __restrict__ dp_w, const float* __restrict__ dp_b,
    const float* __restrict__ A2,
    const float* __restrict__ Pbuf, const float* __restrict__ Fbuf,
    float* __restrict__ resy)            // in: gate, out: gated y
{
    __shared__ float yl_l[CH][64];
    __shared__ float r_l[CH][64];
    __shared__ float c_l[CH][16];
    __shared__ float dlt_l[CH][8];
    __shared__ float dl_l[CH][64];
    __shared__ float dpw_s[64][9];
    __shared__ float dpb_s[64];

    const int tid = threadIdx.x;
    const int bt = blockIdx.x >> 4;
    const int seg = (blockIdx.x >> 1) & 7;
    const int d0 = (blockIdx.x & 1) * 64;
    const int dd = tid >> 2, q = tid & 3;
    const int d = d0 + dd;

    #pragma unroll
    for (int i = 0; i < 2; ++i) {
        int idx = tid + i * 256;
        dpw_s[idx >> 3][idx & 7] = dp_w[(d0 + (idx >> 3)) * 8 + (idx & 7)];
    }
    if (tid < 64) dpb_s[tid] = dp_b[d0 + tid];
    float A2q[4];
    #pragma unroll
    for (int jn = 0; jn < 4; ++jn) A2q[jn] = A2[d * NSTATE + q * 4 + jn];

    // fix-up: x_init = serial combine over segments 0..seg-1
    float xi0 = 0.f, xi1 = 0.f, xi2 = 0.f, xi3 = 0.f;
    for (int s = 0; s < seg; ++s) {
        const size_t idx = ((size_t)(bt * SEG + s) * D + d) * NSTATE + q * 4;
        float4 P = *(const float4*)&Pbuf[idx];
        float4 F = *(const float4*)&Fbuf[idx];
        xi0 = fmaf(P.x, xi0, F.x);
        xi1 = fmaf(P.y, xi1, F.y);
        xi2 = fmaf(P.z, xi2, F.z);
        xi3 = fmaf(P.w, xi3, F.w);
    }

    const size_t segbase = (size_t)bt * T_SEQ + (size_t)seg * SEGLEN;
    float S = 0.f;
    float4 sy, sr, sc, sdl;
    sy = *(const float4*)&ylocal[(segbase + (tid >> 4)) * D + d0 + (tid & 15) * 4];
    sr = *(const float4*)&resy[(segbase + (tid >> 4)) * D + d0 + (tid & 15) * 4];
    if (tid < 64) sc = *(const float4*)&bc[(segbase + (tid >> 2)) * 32 + 16 + (tid & 3) * 4];
    if (tid < 32) sdl = *(const float4*)&dlt[(segbase + (tid >> 1)) * 8 + (tid & 1) * 4];

    for (int c = 0; c < SEGLEN / CH; ++c) {
        const size_t tb = segbase + (size_t)c * CH;
        *(float4*)&yl_l[tid >> 4][(tid & 15) * 4] = sy;
        *(float4*)&r_l[tid >> 4][(tid & 15) * 4] = sr;
        if (tid < 64) *(float4*)&c_l[tid >> 2][(tid & 3) * 4] = sc;
        if (tid < 32) *(float4*)&dlt_l[tid >> 1][(tid & 1) * 4] = sdl;
        __syncthreads();
        if (c + 1 < SEGLEN / CH) {
            const size_t nb = tb + CH;
            sy = *(const float4*)&ylocal[(nb + (tid >> 4)) * D + d0 + (tid & 15) * 4];
            sr = *(const float4*)&resy[(nb + (tid >> 4)) * D + d0 + (tid & 15) * 4];
            if (tid < 64) sc = *(const float4*)&bc[(nb + (tid >> 2)) * 32 + 16 + (tid & 3) * 4];
            if (tid < 32) sdl = *(const float4*)&dlt[(nb + (tid >> 1)) * 8 + (tid & 1) * 4];
        }
        {
            int col = tid & 63;
            #pragma unroll
            for (int i = 0; i < 4; ++i) {
                int row = (tid >> 6) + 4 * i;
                float v = dpb_s[col];
                #pragma unroll
                for (int r = 0; r < DR; ++r) v = fmaf(dlt_l[row][r], dpw_s[col][r], v);
                dl_l[row][col] = softplusf_(v);
            }
        }
        __syncthreads();
        // inclusive prefix of dt (the only carried dependency: 1 add/step)
        float Sv[CH];
        {
            float s = S;
            #pragma unroll
            for (int tl = 0; tl < CH; ++tl) { s += dl_l[tl][dd]; Sv[tl] = s; }
            S = s;
        }
        // parallel correction: fully independent across tl
        float pacc[CH];
        #pragma unroll
        for (int tl = 0; tl < CH; ++tl) {
            float4 Cq = *(const float4*)&c_l[tl][q * 4];
            float p;
            p = (exp2f(A2q[0] * Sv[tl]) * xi0) * Cq.x;
            p = fmaf(exp2f(A2q[1] * Sv[tl]) * xi1, Cq.y, p);
            p = fmaf(exp2f(A2q[2] * Sv[tl]) * xi2, Cq.z, p);
            p = fmaf(exp2f(A2q[3] * Sv[tl]) * xi3, Cq.w, p);
            p += __shfl_xor(p, 1);
            p += __shfl_xor(p, 2);
            pacc[tl] = p;
        }
        if (q == 0) {
            #pragma unroll
            for (int tl = 0; tl < CH; ++tl) {
                float g = r_l[tl][dd];
                float y = yl_l[tl][dd] + pacc[tl];
                resy[(tb + tl) * D + d] = y * (g * sigmoidf_(g));
            }
        }
        __syncthreads();
    }
}

// out_proj + residual via 3-term split-bf16 MFMA: h[t] += y[t] @ out_w.T
__global__ __launch_bounds__(256) void k_outproj(
    const float* __restrict__ y, const short* __restrict__ wh, const short* __restrict__ wl,
    float* __restrict__ h)
{
    __shared__ __align__(16) short ysh[32 * ZS];
    __shared__ __align__(16) short ysl[32 * ZS];
    const int tid = threadIdx.x;
    const int wv = tid >> 6, lane = tid & 63;
    const size_t tb = (size_t)blockIdx.x * 32;

    #pragma unroll
    for (int i = 0; i < 4; ++i) {
        int idx = tid + i * 256;
        int row = idx >> 5, c4 = idx & 31;
        float4 v = *(const float4*)&y[(tb + row) * D + c4 * 4];
        short h0 = f2bf(v.x), h1 = f2bf(v.y), h2 = f2bf(v.z), h3 = f2bf(v.w);
        *(short4*)&ysh[row * ZS + c4 * 4] = make_short4(h0, h1, h2, h3);
        *(short4*)&ysl[row * ZS + c4 * 4] = make_short4(
            f2bf(v.x - bf2f(h0)), f2bf(v.y - bf2f(h1)),
            f2bf(v.z - bf2f(h2)), f2bf(v.w - bf2f(h3)));
    }

    const int colb = wv * 32 + (lane & 15);
    const int kb = (lane >> 4) * 8;
    bf16x8 bw[2][4];
    #pragma unroll
    for (int ct = 0; ct < 2; ++ct)
        #pragma unroll
        for (int kf = 0; kf < 4; ++kf)
            bw[ct][kf] = *(const bf16x8*)&wh[(colb + ct * 16) * 128 + kf * 32 + kb];
    __syncthreads();

    f32x4 acc[2][2];
    #pragma unroll
    for (int b = 0; b < 2; ++b)
        #pragma unroll
        for (int ct = 0; ct < 2; ++ct)
            acc[b][ct] = (f32x4){0.f, 0.f, 0.f, 0.f};

    #pragma unroll
    for (int b = 0; b < 2; ++b) {
        bf16x8 ah[4], al[4];
        const int rbase = (b * 16 + (lane & 15)) * ZS + kb;
        #pragma unroll
        for (int kf = 0; kf < 4; ++kf) {
            ah[kf] = *(const bf16x8*)&ysh[rbase + kf * 32];
            al[kf] = *(const bf16x8*)&ysl[rbase + kf * 32];
        }
        #pragma unroll
        for (int ct = 0; ct < 2; ++ct)
            #pragma unroll
            for (int kf = 0; kf < 4; ++kf) {
                acc[b][ct] = __builtin_amdgcn_mfma_f32_16x16x32_bf16(ah[kf], bw[ct][kf], acc[b][ct], 0, 0, 0);
                acc[b][ct] = __builtin_amdgcn_mfma_f32_16x16x32_bf16(al[kf], bw[ct][kf], acc[b][ct], 0, 0, 0);
            }
    }
    #pragma unroll
    for (int ct = 0; ct < 2; ++ct)
        #pragma unroll
        for (int kf = 0; kf < 4; ++kf)
            bw[ct][kf] = *(const bf16x8*)&wl[(colb + ct * 16) * 128 + kf * 32 + kb];
    #pragma unroll
    for (int b = 0; b < 2; ++b) {
        bf16x8 ah[4];
        const int rbase = (b * 16 + (lane & 15)) * ZS + kb;
        #pragma unroll
        for (int kf = 0; kf < 4; ++kf)
            ah[kf] = *(const bf16x8*)&ysh[rbase + kf * 32];
        #pragma unroll
        for (int ct = 0; ct < 2; ++ct)
            #pragma unroll
            for (int kf = 0; kf < 4; ++kf)
                acc[b][ct] = __builtin_amdgcn_mfma_f32_16x16x32_bf16(ah[kf], bw[ct][kf], acc[b][ct], 0, 0, 0);
    }

    #pragma unroll
    for (int b = 0; b < 2; ++b)
        #pragma unroll
        for (int ct = 0; ct < 2; ++ct) {
            const int col = wv * 32 + ct * 16 + (lane & 15);
            #pragma unroll
            for (int i = 0; i < 4; ++i) {
                int row = b * 16 + ((lane >> 4) << 2) + i;
                size_t o = (tb + row) * D + col;
                h[o] += acc[b][ct][i];
            }
        }
}

// out[t] = h[t] . outp_w + outp_b  (one wave per token)
__global__ __launch_bounds__(256) void k_final(
    const float* __restrict__ h, const float* __restrict__ outp_w,
    const float* __restrict__ outp_b, float* __restrict__ out)
{
    const int tid = threadIdx.x;
    const int lane = tid & 63;
    const size_t tok = (size_t)blockIdx.x * 4 + (tid >> 6);
    float a = h[tok * D + lane] * outp_w[lane] + h[tok * D + lane + 64] * outp_w[lane + 64];
    #pragma unroll
    for (int m = 1; m < 64; m <<= 1) a += __shfl_xor(a, m);
    if (lane == 0) out[tok] = a + outp_b[0];
}

extern "C" void kernel_launch(void* const* d_in, const int* in_sizes, int n_in,
                              void* d_out, int out_size, void* d_ws, size_t ws_size,
                              hipStream_t stream)
{
    const float* x      = (const float*)d_in[0];
    const float* inp_w  = (const float*)d_in[1];
    const float* inp_b  = (const float*)d_in[2];
    const float* outp_w = (const float*)d_in[3];
    const float* outp_b = (const float*)d_in[4];
    const float* ln_g   = (const float*)d_in[5];
    const float* ln_b   = (const float*)d_in[6];
    const float* in_w   = (const float*)d_in[7];
    const float* conv_w = (const float*)d_in[8];
    const float* conv_b = (const float*)d_in[9];
    const float* xp_w   = (const float*)d_in[10];
    const float* dp_w   = (const float*)d_in[11];
    const float* dp_b   = (const float*)d_in[12];
    const float* A_log  = (const float*)d_in[13];
    const float* Dp     = (const float*)d_in[14];
    const float* out_w  = (const float*)d_in[15];

    float* ws = (float*)d_ws;
    size_t off = 0;
    float* h      = ws + off; off += (size_t)NTOK * D;
    float* xc     = ws + off; off += (size_t)NTOK * D;   // u, then y_local in-place
    float* resy   = ws + off; off += (size_t)NTOK * D;   // gate in, gated y out
    float* bc     = ws + off; off += (size_t)NTOK * 32;
    float* dlt    = ws + off; off += (size_t)NTOK * 8;
    float* Pbuf   = ws + off; off += 128 * SEG * 2048;
    float* Fbuf   = ws + off; off += 128 * SEG * 2048;
    short* in_wBh = (short*)(ws + off); off += 4 * 256 * 128 / 2;
    short* in_wBl = (short*)(ws + off); off += 4 * 256 * 128 / 2;
    short* out_wBh= (short*)(ws + off); off += 4 * 128 * 128 / 2;
    short* out_wBl= (short*)(ws + off); off += 4 * 128 * 128 / 2;
    short* xp_wBh = (short*)(ws + off); off += 4 * 48 * 128 / 2;
    short* xp_wBl = (short*)(ws + off); off += 4 * 48 * 128 / 2;
    float* A2     = ws + off; off += 4 * 128 * 16;
    if (ws_size < off * sizeof(float)) return;  // workspace too small -> fail visibly

    // prep
    k_prepw<<<(4 * 256 * 128 + 255) / 256, 256, 0, stream>>>(in_w, in_wBh, in_wBl, 4 * 256 * 128);
    k_prepw<<<(4 * 128 * 128 + 255) / 256, 256, 0, stream>>>(out_w, out_wBh, out_wBl, 4 * 128 * 128);
    k_prepw_xp<<<(4 * 48 * 128 + 255) / 256, 256, 0, stream>>>(xp_w, xp_wBh, xp_wBl);
    k_a2<<<(4 * 128 * 16 + 255) / 256, 256, 0, stream>>>(A_log, A2, 4 * 128 * 16);
    k_init_h<<<NTOK * D / 256, 256, 0, stream>>>(x, inp_w, inp_b, h);

    for (int l = 0; l < 4; ++l) {
        k_ln_inproj_conv<<<NTOK / 32, 256, 0, stream>>>(
            h, ln_g + l * 128, ln_b + l * 128,
            in_wBh + l * 256 * 128, in_wBl + l * 256 * 128,
            xp_wBh + l * 48 * 128, xp_wBl + l * 48 * 128,
            conv_w + l * 128 * 3, conv_b + l * 128, xc, resy, bc, dlt);
        k_scanA<<<2048, 256, 0, stream>>>(xc, bc, dlt, dp_w + l * 128 * 8, dp_b + l * 128,
                                          A2 + l * 128 * 16, Dp + l * 128, Pbuf, Fbuf);
        k_scanB<<<2048, 256, 0, stream>>>(xc, bc, dlt, dp_w + l * 128 * 8, dp_b + l * 128,
                                          A2 + l * 128 * 16, Pbuf, Fbuf, resy);
        k_outproj<<<NTOK / 32, 256, 0, stream>>>(resy, out_wBh + l * 128 * 128,
                                                 out_wBl + l * 128 * 128, h);
    }
    k_final<<<NTOK / 4, 256, 0, stream>>>(h, outp_w, outp_b, (float*)d_out);
}

// Round 13
// 1526.652 us; speedup vs baseline: 1.0294x; 1.0294x over previous
//
#include <hip/hip_runtime.h>
#include <math.h>

#define D 128
#define NSTATE 16
#define DR 8
#define T_SEQ 1024
#define NTOK 131072  // 128 sequences * 1024 tokens
#define SEG 8        // segments per sequence (parallel scan)
#define SEGLEN 128   // T_SEQ / SEG
#define CH 16        // chunk (timesteps staged in LDS at once)
#define ZS 136       // bf16 elems per z row (128 + 8 pad -> 272B stride)
#define XRS2 132     // f32 elems per xr row (128 + 4 pad)

typedef __attribute__((ext_vector_type(8))) short bf16x8;
typedef __attribute__((ext_vector_type(4))) float f32x4;

#define LOG2E 1.44269504088896340736f
#define LN2   0.69314718055994530942f

// fast sigmoid: 1/(1+2^(-x*log2e)) via v_exp + v_rcp (~1 ulp)
__device__ __forceinline__ float sigmoidf_(float x) {
    return __builtin_amdgcn_rcpf(1.0f + exp2f(-x * LOG2E));
}
// fast softplus: ln2 * log2(1 + 2^(x*log2e)) via v_exp + v_log
__device__ __forceinline__ float softplusf_(float x) {
    float t = LN2 * __builtin_amdgcn_logf(1.0f + exp2f(x * LOG2E));
    return (x > 20.0f) ? x : t;
}
__device__ __forceinline__ short f2bf(float f) {   // RNE float->bf16
    union { float f; unsigned u; } v; v.f = f;
    unsigned r = v.u + 0x7FFFu + ((v.u >> 16) & 1u);
    return (short)(r >> 16);
}
__device__ __forceinline__ float bf2f(short s) {
    union { unsigned u; float f; } v; v.u = ((unsigned)(unsigned short)s) << 16;
    return v.f;
}

// ---------------- prep kernels ----------------

// f32 -> bf16 hi/lo split, elementwise (layout preserved)
__global__ void k_prepw(const float* __restrict__ src, short* __restrict__ hi,
                        short* __restrict__ lo, int n) {
    int i = blockIdx.x * 256 + threadIdx.x;
    if (i < n) {
        float f = src[i];
        short hh = f2bf(f);
        hi[i] = hh;
        lo[i] = f2bf(f - bf2f(hh));
    }
}

// xp_w (L,40,128) -> padded (L,48,128) bf16 hi/lo, rows 40..47 zero
__global__ void k_prepw_xp(const float* __restrict__ src, short* __restrict__ hi,
                           short* __restrict__ lo) {
    int i = blockIdx.x * 256 + threadIdx.x;     // over 4*48*128
    if (i >= 4 * 48 * 128) return;
    int l = i / (48 * 128);
    int rem = i - l * 48 * 128;
    int j = rem >> 7, k = rem & 127;
    float f = (j < 40) ? src[(l * 40 + j) * 128 + k] : 0.f;
    short hh = f2bf(f);
    hi[i] = hh;
    lo[i] = f2bf(f - bf2f(hh));
}

// A2 = -exp(A_log) * log2(e)
__global__ void k_a2(const float* __restrict__ A_log, float* __restrict__ A2, int total) {
    int idx = blockIdx.x * blockDim.x + threadIdx.x;
    if (idx < total) A2[idx] = -__expf(A_log[idx]) * LOG2E;
}

// h[tok][d] = x[tok] * inp_w[d] + inp_b[d]
__global__ void k_init_h(const float* __restrict__ x, const float* __restrict__ inp_w,
                         const float* __restrict__ inp_b, float* __restrict__ h) {
    int idx = blockIdx.x * blockDim.x + threadIdx.x;
    int tok = idx >> 7;
    int d = idx & 127;
    h[idx] = x[tok] * inp_w[d] + inp_b[d];
}

// ---------------- per-layer kernels ----------------
// Fused LN + in_proj (3-term split-bf16 MFMA) + causal conv(k=3) + SiLU
// + x_proj (second MFMA stage) -> xc, res, bc, dlt. ALL global stores
// routed through LDS for full coalescing (res rows 512B, bc 4KB, dlt 1KB).
__global__ __launch_bounds__(256) void k_ln_inproj_conv(
    const float* __restrict__ h, const float* __restrict__ ln_g, const float* __restrict__ ln_b,
    const short* __restrict__ wh, const short* __restrict__ wl,   // in_proj (256,128) hi/lo
    const short* __restrict__ xph, const short* __restrict__ xpl, // x_proj padded (48,128) hi/lo
    const float* __restrict__ conv_w, const float* __restrict__ conv_b,
    float* __restrict__ xc, float* __restrict__ res,
    float* __restrict__ bc, float* __restrict__ dlt)
{
    __shared__ __align__(16) short zsh[48 * ZS];
    __shared__ __align__(16) short zsl[48 * ZS];
    __shared__ __align__(16) float xr[34 * XRS2];
    __shared__ __align__(16) float dbc_l[32][52];   // stage-2 out (40 used, 52 stride)
    const int tid = threadIdx.x;
    const int wv = tid >> 6, lane = tid & 63;
    const int tstart = blockIdx.x * 32;
    const int tin = tstart & (T_SEQ - 1);

    // Phase A: LayerNorm rows 0..33 -> bf16 hi/lo
    for (int r = wv; r < 34; r += 4) {
        int tr = tin + r - 2;
        if (tr < 0) {
            zsh[r * ZS + lane] = 0; zsh[r * ZS + lane + 64] = 0;
            zsl[r * ZS + lane] = 0; zsl[r * ZS + lane + 64] = 0;
            continue;
        }
        size_t row = (size_t)(tstart + r - 2) * D;
        float a = h[row + lane];
        float b = h[row + lane + 64];
        float s = a + b, ss = a * a + b * b;
        #pragma unroll
        for (int m = 1; m < 64; m <<= 1) { s += __shfl_xor(s, m); ss += __shfl_xor(ss, m); }
        float mu = s * (1.0f / 128.0f);
        float var = ss * (1.0f / 128.0f) - mu * mu;
        float rstd = rsqrtf(var + 1e-5f);
        float z0 = (a - mu) * rstd * ln_g[lane]      + ln_b[lane];
        float z1 = (b - mu) * rstd * ln_g[lane + 64] + ln_b[lane + 64];
        short h0 = f2bf(z0), h1 = f2bf(z1);
        zsh[r * ZS + lane]      = h0;
        zsh[r * ZS + lane + 64] = h1;
        zsl[r * ZS + lane]      = f2bf(z0 - bf2f(h0));
        zsl[r * ZS + lane + 64] = f2bf(z1 - bf2f(h1));
    }
    for (int i = tid; i < 14 * 128; i += 256) {
        int r = 34 + (i >> 7), c = i & 127;
        zsh[r * ZS + c] = 0;
        zsl[r * ZS + c] = 0;
    }

    // B panel (hi) -> registers
    const int colb = wv * 64 + (lane & 15);
    const int kb = (lane >> 4) * 8;
    bf16x8 bw[4][4];
    #pragma unroll
    for (int ct = 0; ct < 4; ++ct)
        #pragma unroll
        for (int kf = 0; kf < 4; ++kf)
            bw[ct][kf] = *(const bf16x8*)&wh[(colb + ct * 16) * 128 + kf * 32 + kb];
    __syncthreads();

    f32x4 acc[3][4];
    #pragma unroll
    for (int b = 0; b < 3; ++b)
        #pragma unroll
        for (int ct = 0; ct < 4; ++ct)
            acc[b][ct] = (f32x4){0.f, 0.f, 0.f, 0.f};

    // Pass 1: (a_hi + a_lo) * b_hi
    #pragma unroll
    for (int b = 0; b < 3; ++b) {
        bf16x8 ah[4], al[4];
        const int rbase = (b * 16 + (lane & 15)) * ZS + kb;
        #pragma unroll
        for (int kf = 0; kf < 4; ++kf) {
            ah[kf] = *(const bf16x8*)&zsh[rbase + kf * 32];
            al[kf] = *(const bf16x8*)&zsl[rbase + kf * 32];
        }
        #pragma unroll
        for (int ct = 0; ct < 4; ++ct)
            #pragma unroll
            for (int kf = 0; kf < 4; ++kf) {
                acc[b][ct] = __builtin_amdgcn_mfma_f32_16x16x32_bf16(ah[kf], bw[ct][kf], acc[b][ct], 0, 0, 0);
                acc[b][ct] = __builtin_amdgcn_mfma_f32_16x16x32_bf16(al[kf], bw[ct][kf], acc[b][ct], 0, 0, 0);
            }
    }
    // Pass 2: a_hi * b_lo
    #pragma unroll
    for (int ct = 0; ct < 4; ++ct)
        #pragma unroll
        for (int kf = 0; kf < 4; ++kf)
            bw[ct][kf] = *(const bf16x8*)&wl[(colb + ct * 16) * 128 + kf * 32 + kb];
    #pragma unroll
    for (int b = 0; b < 3; ++b) {
        bf16x8 ah[4];
        const int rbase = (b * 16 + (lane & 15)) * ZS + kb;
        #pragma unroll
        for (int kf = 0; kf < 4; ++kf)
            ah[kf] = *(const bf16x8*)&zsh[rbase + kf * 32];
        #pragma unroll
        for (int ct = 0; ct < 4; ++ct)
            #pragma unroll
            for (int kf = 0; kf < 4; ++kf)
                acc[b][ct] = __builtin_amdgcn_mfma_f32_16x16x32_bf16(ah[kf], bw[ct][kf], acc[b][ct], 0, 0, 0);
    }

    // conv-half acc (waves 0-1) -> xr; gate half stays in registers
    if (wv < 2) {
        #pragma unroll
        for (int b = 0; b < 3; ++b)
            #pragma unroll
            for (int ct = 0; ct < 4; ++ct) {
                const int col = wv * 64 + ct * 16 + (lane & 15);
                #pragma unroll
                for (int i = 0; i < 4; ++i) {
                    int row = b * 16 + ((lane >> 4) << 2) + i;
                    if (row < 34) xr[row * XRS2 + col] = acc[b][ct][i];
                }
            }
    }
    __syncthreads();

    // Epilogue: conv+silu -> xc (coalesced) + bf16 split into zsh/zsl rows 0..31
    if (tid < 128) {
        float c0 = conv_w[tid * 3 + 0], c1 = conv_w[tid * 3 + 1], c2 = conv_w[tid * 3 + 2];
        float cb = conv_b[tid];
        float v0 = xr[0 * XRS2 + tid], v1 = xr[1 * XRS2 + tid];
        #pragma unroll
        for (int s = 0; s < 32; ++s) {
            float v2 = xr[(s + 2) * XRS2 + tid];
            float v = v0 * c0 + v1 * c1 + v2 * c2 + cb;
            v = v * sigmoidf_(v);
            xc[(size_t)(tstart + s) * D + tid] = v;
            short hh = f2bf(v);
            zsh[s * ZS + tid] = hh;
            zsl[s * ZS + tid] = f2bf(v - bf2f(hh));
            v0 = v1; v1 = v2;
        }
    }
    __syncthreads();

    // gate-half acc (waves 2-3) -> xr rows 2..33 (xr free now);
    // concurrently all waves run stage-2 MFMA -> dbc_l LDS.
    if (wv >= 2) {
        #pragma unroll
        for (int b = 0; b < 3; ++b)
            #pragma unroll
            for (int ct = 0; ct < 4; ++ct) {
                const int col = (wv - 2) * 64 + ct * 16 + (lane & 15);
                #pragma unroll
                for (int i = 0; i < 4; ++i) {
                    int row = b * 16 + ((lane >> 4) << 2) + i;
                    if (row >= 2 && row < 34) xr[row * XRS2 + col] = acc[b][ct][i];
                }
            }
    }
    // Stage 2 MFMA: dbc = xc @ xp_w.T (M=32, N=48 padded, K=128), 3-term split.
    for (int tile = wv; tile < 6; tile += 4) {
        const int b = tile & 1, ct = tile >> 1;
        const int jcol = ct * 16 + (lane & 15);
        const int rbase = (b * 16 + (lane & 15)) * ZS + kb;
        bf16x8 ah[4], al[4], bh[4];
        #pragma unroll
        for (int kf = 0; kf < 4; ++kf) {
            ah[kf] = *(const bf16x8*)&zsh[rbase + kf * 32];
            al[kf] = *(const bf16x8*)&zsl[rbase + kf * 32];
            bh[kf] = *(const bf16x8*)&xph[jcol * 128 + kf * 32 + kb];
        }
        f32x4 a2 = (f32x4){0.f, 0.f, 0.f, 0.f};
        #pragma unroll
        for (int kf = 0; kf < 4; ++kf) {
            a2 = __builtin_amdgcn_mfma_f32_16x16x32_bf16(ah[kf], bh[kf], a2, 0, 0, 0);
            a2 = __builtin_amdgcn_mfma_f32_16x16x32_bf16(al[kf], bh[kf], a2, 0, 0, 0);
        }
        #pragma unroll
        for (int kf = 0; kf < 4; ++kf) {
            bh[kf] = *(const bf16x8*)&xpl[jcol * 128 + kf * 32 + kb];
            a2 = __builtin_amdgcn_mfma_f32_16x16x32_bf16(ah[kf], bh[kf], a2, 0, 0, 0);
        }
        #pragma unroll
        for (int i = 0; i < 4; ++i) {
            int t = b * 16 + ((lane >> 4) << 2) + i;
            dbc_l[t][jcol] = a2[i];
        }
    }
    __syncthreads();

    // Coalesced flush: res (32 x 512B), bc (4KB contig), dlt (1KB contig)
    for (int fi = tid; fi < 1024; fi += 256) {
        int r = fi >> 5, c4 = fi & 31;
        *(float4*)&res[(size_t)(tstart + r) * D + c4 * 4] =
            *(const float4*)&xr[(r + 2) * XRS2 + c4 * 4];
    }
    {
        int t = tid >> 3, q = tid & 7;
        *(float4*)&bc[(size_t)(tstart + t) * 32 + q * 4] = *(const float4*)&dbc_l[t][8 + q * 4];
    }
    if (tid < 64) {
        int t = tid >> 1, j4 = tid & 1;
        *(float4*)&dlt[(size_t)(tstart + t) * 8 + j4 * 4] = *(const float4*)&dbc_l[t][j4 * 4];
    }
}

// ---- chunk-parallel selective scan (round-11 known-good) ----
// Pass 1: per-segment scan from x=0 -> F, P. Grid 2048 x 256. B-half staging only.
__global__ __launch_bounds__(256) void k_scan1(
    const float* __restrict__ xc, const float* __restrict__ bc,
    const float* __restrict__ dlt,
    const float* __restrict__ dp_w, const float* __restrict__ dp_b,
    const float* __restrict__ A2,
    float* __restrict__ Pbuf, float* __restrict__ Fbuf)
{
    __shared__ float u_l[CH][64];
    __shared__ float du_l[CH][64];
    __shared__ float bc_l[CH][16];
    __shared__ float dlt_l[CH][8];
    __shared__ float dl_l[CH][64];
    __shared__ float dpw_s[64][9];
    __shared__ float dpb_s[64];

    const int tid = threadIdx.x;
    const int bt = blockIdx.x >> 4;
    const int seg = (blockIdx.x >> 1) & 7;
    const int d0 = (blockIdx.x & 1) * 64;
    const int dd = tid >> 2, q = tid & 3;
    const int d = d0 + dd;

    #pragma unroll
    for (int i = 0; i < 2; ++i) {
        int idx = tid + i * 256;
        dpw_s[idx >> 3][idx & 7] = dp_w[(d0 + (idx >> 3)) * 8 + (idx & 7)];
    }
    if (tid < 64) dpb_s[tid] = dp_b[d0 + tid];
    float A2q[4];
    #pragma unroll
    for (int jn = 0; jn < 4; ++jn) A2q[jn] = A2[d * NSTATE + q * 4 + jn];
    float x0 = 0.f, x1 = 0.f, x2 = 0.f, x3 = 0.f, S = 0.f;

    const size_t segbase = (size_t)bt * T_SEQ + (size_t)seg * SEGLEN;
    float4 su, sbc, sdl;
    su = *(const float4*)&xc[(segbase + (tid >> 4)) * D + d0 + (tid & 15) * 4];
    if (tid < 64)  sbc = *(const float4*)&bc[(segbase + (tid >> 2)) * 32 + (tid & 3) * 4];
    if (tid < 32)  sdl = *(const float4*)&dlt[(segbase + (tid >> 1)) * 8 + (tid & 1) * 4];

    for (int c = 0; c < SEGLEN / CH; ++c) {
        *(float4*)&u_l[tid >> 4][(tid & 15) * 4] = su;
        if (tid < 64)  *(float4*)&bc_l[tid >> 2][(tid & 3) * 4] = sbc;
        if (tid < 32)  *(float4*)&dlt_l[tid >> 1][(tid & 1) * 4] = sdl;
        __syncthreads();
        if (c + 1 < SEGLEN / CH) {
            const size_t nb = segbase + (size_t)(c + 1) * CH;
            su = *(const float4*)&xc[(nb + (tid >> 4)) * D + d0 + (tid & 15) * 4];
            if (tid < 64)  sbc = *(const float4*)&bc[(nb + (tid >> 2)) * 32 + (tid & 3) * 4];
            if (tid < 32)  sdl = *(const float4*)&dlt[(nb + (tid >> 1)) * 8 + (tid & 1) * 4];
        }
        {
            int col = tid & 63;
            #pragma unroll
            for (int i = 0; i < 4; ++i) {
                int row = (tid >> 6) + 4 * i;
                float v = dpb_s[col];
                #pragma unroll
                for (int r = 0; r < DR; ++r) v = fmaf(dlt_l[row][r], dpw_s[col][r], v);
                float dt = softplusf_(v);
                dl_l[row][col] = dt;
                du_l[row][col] = dt * u_l[row][col];
            }
        }
        __syncthreads();
        #pragma unroll
        for (int tl = 0; tl < CH; ++tl) {
            float dt = dl_l[tl][dd];
            float duv = du_l[tl][dd];
            S += dt;
            float4 Bq = *(const float4*)&bc_l[tl][q * 4];
            x0 = fmaf(exp2f(dt * A2q[0]), x0, duv * Bq.x);
            x1 = fmaf(exp2f(dt * A2q[1]), x1, duv * Bq.y);
            x2 = fmaf(exp2f(dt * A2q[2]), x2, duv * Bq.z);
            x3 = fmaf(exp2f(dt * A2q[3]), x3, duv * Bq.w);
        }
        __syncthreads();
    }
    const size_t o = ((size_t)(bt * SEG + seg) * D + d) * NSTATE + q * 4;
    *(float4*)&Fbuf[o] = make_float4(x0, x1, x2, x3);
    *(float4*)&Pbuf[o] = make_float4(exp2f(A2q[0] * S), exp2f(A2q[1] * S),
                                     exp2f(A2q[2] * S), exp2f(A2q[3] * S));
}

// Pass 2: inline fix-up then re-scan; y = C.x + u*Dp, gated, stored over res.
__global__ __launch_bounds__(256) void k_scan2(
    const float* __restrict__ xc, const float* __restrict__ bc,
    const float* __restrict__ dlt,
    const float* __restrict__ dp_w, const float* __restrict__ dp_b,
    const float* __restrict__ A2, const float* __restrict__ Dp,
    const float* __restrict__ Pbuf, const float* __restrict__ Fbuf,
    float* __restrict__ resy)
{
    __shared__ float u_l[CH][64];
    __shared__ float r_l[CH][64];
    __shared__ float bc_l[CH][32];
    __shared__ float dlt_l[CH][8];
    __shared__ float dl_l[CH][64];
    __shared__ float dpw_s[64][9];
    __shared__ float dpb_s[64];

    const int tid = threadIdx.x;
    const int bt = blockIdx.x >> 4;
    const int seg = (blockIdx.x >> 1) & 7;
    const int d0 = (blockIdx.x & 1) * 64;
    const int dd = tid >> 2, q = tid & 3;
    const int d = d0 + dd;

    #pragma unroll
    for (int i = 0; i < 2; ++i) {
        int idx = tid + i * 256;
        dpw_s[idx >> 3][idx & 7] = dp_w[(d0 + (idx >> 3)) * 8 + (idx & 7)];
    }
    if (tid < 64) dpb_s[tid] = dp_b[d0 + tid];
    float A2q[4];
    #pragma unroll
    for (int jn = 0; jn < 4; ++jn) A2q[jn] = A2[d * NSTATE + q * 4 + jn];
    const float Dpd = Dp[d];

    // inline fix-up: x_init = serial combine over segments 0..seg-1
    float x0 = 0.f, x1 = 0.f, x2 = 0.f, x3 = 0.f;
    for (int s = 0; s < seg; ++s) {
        const size_t idx = ((size_t)(bt * SEG + s) * D + d) * NSTATE + q * 4;
        float4 P = *(const float4*)&Pbuf[idx];
        float4 F = *(const float4*)&Fbuf[idx];
        x0 = fmaf(P.x, x0, F.x);
        x1 = fmaf(P.y, x1, F.y);
        x2 = fmaf(P.z, x2, F.z);
        x3 = fmaf(P.w, x3, F.w);
    }

    const size_t segbase = (size_t)bt * T_SEQ + (size_t)seg * SEGLEN;
    float4 su, sr, sbc, sdl;
    su = *(const float4*)&xc[(segbase + (tid >> 4)) * D + d0 + (tid & 15) * 4];
    sr = *(const float4*)&resy[(segbase + (tid >> 4)) * D + d0 + (tid & 15) * 4];
    if (tid < 128) sbc = *(const float4*)&bc[(segbase + (tid >> 3)) * 32 + (tid & 7) * 4];
    if (tid < 32)  sdl = *(const float4*)&dlt[(segbase + (tid >> 1)) * 8 + (tid & 1) * 4];

    for (int c = 0; c < SEGLEN / CH; ++c) {
        const size_t tb = segbase + (size_t)c * CH;
        *(float4*)&u_l[tid >> 4][(tid & 15) * 4] = su;
        *(float4*)&r_l[tid >> 4][(tid & 15) * 4] = sr;
        if (tid < 128) *(float4*)&bc_l[tid >> 3][(tid & 7) * 4] = sbc;
        if (tid < 32)  *(float4*)&dlt_l[tid >> 1][(tid & 1) * 4] = sdl;
        __syncthreads();
        if (c + 1 < SEGLEN / CH) {
            const size_t nb = tb + CH;
            su = *(const float4*)&xc[(nb + (tid >> 4)) * D + d0 + (tid & 15) * 4];
            sr = *(const float4*)&resy[(nb + (tid >> 4)) * D + d0 + (tid & 15) * 4];
            if (tid < 128) sbc = *(const float4*)&bc[(nb + (tid >> 3)) * 32 + (tid & 7) * 4];
            if (tid < 32)  sdl = *(const float4*)&dlt[(nb + (tid >> 1)) * 8 + (tid & 1) * 4];
        }
        {
            int col = tid & 63;
            #pragma unroll
            for (int i = 0; i < 4; ++i) {
                int row = (tid >> 6) + 4 * i;
                float v = dpb_s[col];
                #pragma unroll
                for (int r = 0; r < DR; ++r) v = fmaf(dlt_l[row][r], dpw_s[col][r], v);
                dl_l[row][col] = softplusf_(v);
            }
        }
        __syncthreads();
        float pacc[CH];
        #pragma unroll
        for (int tl = 0; tl < CH; ++tl) {
            float dt = dl_l[tl][dd];
            float uv = u_l[tl][dd];
            float duv = dt * uv;
            float4 Bq = *(const float4*)&bc_l[tl][q * 4];
            float4 Cq = *(const float4*)&bc_l[tl][16 + q * 4];
            x0 = fmaf(exp2f(dt * A2q[0]), x0, duv * Bq.x);
            x1 = fmaf(exp2f(dt * A2q[1]), x1, duv * Bq.y);
            x2 = fmaf(exp2f(dt * A2q[2]), x2, duv * Bq.z);
            x3 = fmaf(exp2f(dt * A2q[3]), x3, duv * Bq.w);
            float p = x0 * Cq.x;
            p = fmaf(x1, Cq.y, p);
            p = fmaf(x2, Cq.z, p);
            p = fmaf(x3, Cq.w, p);
            p += __shfl_xor(p, 1);
            p += __shfl_xor(p, 2);
            pacc[tl] = fmaf(uv, Dpd, p);
        }
        if (q == 0) {
            #pragma unroll
            for (int tl = 0; tl < CH; ++tl) {
                float g = r_l[tl][dd];
                resy[(tb + tl) * D + d] = pacc[tl] * (g * sigmoidf_(g));
            }
        }
        __syncthreads();
    }
}

// out_proj + residual via 3-term split-bf16 MFMA: h[t] += y[t] @ out_w.T
__global__ __launch_bounds__(256) void k_outproj(
    const float* __restrict__ y, const short* __restrict__ wh, const short* __restrict__ wl,
    float* __restrict__ h)
{
    __shared__ __align__(16) short ysh[32 * ZS];
    __shared__ __align__(16) short ysl[32 * ZS];
    const int tid = threadIdx.x;
    const int wv = tid >> 6, lane = tid & 63;
    const size_t tb = (size_t)blockIdx.x * 32;

    #pragma unroll
    for (int i = 0; i < 4; ++i) {
        int idx = tid + i * 256;
        int row = idx >> 5, c4 = idx & 31;
        float4 v = *(const float4*)&y[(tb + row) * D + c4 * 4];
        short h0 = f2bf(v.x), h1 = f2bf(v.y), h2 = f2bf(v.z), h3 = f2bf(v.w);
        *(short4*)&ysh[row * ZS + c4 * 4] = make_short4(h0, h1, h2, h3);
        *(short4*)&ysl[row * ZS + c4 * 4] = make_short4(
            f2bf(v.x - bf2f(h0)), f2bf(v.y - bf2f(h1)),
            f2bf(v.z - bf2f(h2)), f2bf(v.w - bf2f(h3)));
    }

    const int colb = wv * 32 + (lane & 15);
    const int kb = (lane >> 4) * 8;
    bf16x8 bw[2][4];
    #pragma unroll
    for (int ct = 0; ct < 2; ++ct)
        #pragma unroll
        for (int kf = 0; kf < 4; ++kf)
            bw[ct][kf] = *(const bf16x8*)&wh[(colb + ct * 16) * 128 + kf * 32 + kb];
    __syncthreads();

    f32x4 acc[2][2];
    #pragma unroll
    for (int b = 0; b < 2; ++b)
        #pragma unroll
        for (int ct = 0; ct < 2; ++ct)
            acc[b][ct] = (f32x4){0.f, 0.f, 0.f, 0.f};

    #pragma unroll
    for (int b = 0; b < 2; ++b) {
        bf16x8 ah[4], al[4];
        const int rbase = (b * 16 + (lane & 15)) * ZS + kb;
        #pragma unroll
        for (int kf = 0; kf < 4; ++kf) {
            ah[kf] = *(const bf16x8*)&ysh[rbase + kf * 32];
            al[kf] = *(const bf16x8*)&ysl[rbase + kf * 32];
        }
        #pragma unroll
        for (int ct = 0; ct < 2; ++ct)
            #pragma unroll
            for (int kf = 0; kf < 4; ++kf) {
                acc[b][ct] = __builtin_amdgcn_mfma_f32_16x16x32_bf16(ah[kf], bw[ct][kf], acc[b][ct], 0, 0, 0);
                acc[b][ct] = __builtin_amdgcn_mfma_f32_16x16x32_bf16(al[kf], bw[ct][kf], acc[b][ct], 0, 0, 0);
            }
    }
    #pragma unroll
    for (int ct = 0; ct < 2; ++ct)
        #pragma unroll
        for (int kf = 0; kf < 4; ++kf)
            bw[ct][kf] = *(const bf16x8*)&wl[(colb + ct * 16) * 128 + kf * 32 + kb];
    #pragma unroll
    for (int b = 0; b < 2; ++b) {
        bf16x8 ah[4];
        const int rbase = (b * 16 + (lane & 15)) * ZS + kb;
        #pragma unroll
        for (int kf = 0; kf < 4; ++kf)
            ah[kf] = *(const bf16x8*)&ysh[rbase + kf * 32];
        #pragma unroll
        for (int ct = 0; ct < 2; ++ct)
            #pragma unroll
            for (int kf = 0; kf < 4; ++kf)
                acc[b][ct] = __builtin_amdgcn_mfma_f32_16x16x32_bf16(ah[kf], bw[ct][kf], acc[b][ct], 0, 0, 0);
    }

    #pragma unroll
    for (int b = 0; b < 2; ++b)
        #pragma unroll
        for (int ct = 0; ct < 2; ++ct) {
            const int col = wv * 32 + ct * 16 + (lane & 15);
            #pragma unroll
            for (int i = 0; i < 4; ++i) {
                int row = b * 16 + ((lane >> 4) << 2) + i;
                size_t o = (tb + row) * D + col;
                h[o] += acc[b][ct][i];
            }
        }
}

// out[t] = h[t] . outp_w + outp_b  (one wave per token)
__global__ __launch_bounds__(256) void k_final(
    const float* __restrict__ h, const float* __restrict__ outp_w,
    const float* __restrict__ outp_b, float* __restrict__ out)
{
    const int tid = threadIdx.x;
    const int lane = tid & 63;
    const size_t tok = (size_t)blockIdx.x * 4 + (tid >> 6);
    float a = h[tok * D + lane] * outp_w[lane] + h[tok * D + lane + 64] * outp_w[lane + 64];
    #pragma unroll
    for (int m = 1; m < 64; m <<= 1) a += __shfl_xor(a, m);
    if (lane == 0) out[tok] = a + outp_b[0];
}

extern "C" void kernel_launch(void* const* d_in, const int* in_sizes, int n_in,
                              void* d_out, int out_size, void* d_ws, size_t ws_size,
                              hipStream_t stream)
{
    const float* x      = (const float*)d_in[0];
    const float* inp_w  = (const float*)d_in[1];
    const float* inp_b  = (const float*)d_in[2];
    const float* outp_w = (const float*)d_in[3];
    const float* outp_b = (const float*)d_in[4];
    const float* ln_g   = (const float*)d_in[5];
    const float* ln_b   = (const float*)d_in[6];
    const float* in_w   = (const float*)d_in[7];
    const float* conv_w = (const float*)d_in[8];
    const float* conv_b = (const float*)d_in[9];
    const float* xp_w   = (const float*)d_in[10];
    const float* dp_w   = (const float*)d_in[11];
    const float* dp_b   = (const float*)d_in[12];
    const float* A_log  = (const float*)d_in[13];
    const float* Dp     = (const float*)d_in[14];
    const float* out_w  = (const float*)d_in[15];

    float* ws = (float*)d_ws;
    size_t off = 0;
    float* h      = ws + off; off += (size_t)NTOK * D;
    float* xc     = ws + off; off += (size_t)NTOK * D;
    float* resy   = ws + off; off += (size_t)NTOK * D;
    float* bc     = ws + off; off += (size_t)NTOK * 32;
    float* dlt    = ws + off; off += (size_t)NTOK * 8;
    float* Pbuf   = ws + off; off += 128 * SEG * 2048;
    float* Fbuf   = ws + off; off += 128 * SEG * 2048;
    short* in_wBh = (short*)(ws + off); off += 4 * 256 * 128 / 2;
    short* in_wBl = (short*)(ws + off); off += 4 * 256 * 128 / 2;
    short* out_wBh= (short*)(ws + off); off += 4 * 128 * 128 / 2;
    short* out_wBl= (short*)(ws + off); off += 4 * 128 * 128 / 2;
    short* xp_wBh = (short*)(ws + off); off += 4 * 48 * 128 / 2;
    short* xp_wBl = (short*)(ws + off); off += 4 * 48 * 128 / 2;
    float* A2     = ws + off; off += 4 * 128 * 16;
    if (ws_size < off * sizeof(float)) return;  // workspace too small -> fail visibly

    // prep
    k_prepw<<<(4 * 256 * 128 + 255) / 256, 256, 0, stream>>>(in_w, in_wBh, in_wBl, 4 * 256 * 128);
    k_prepw<<<(4 * 128 * 128 + 255) / 256, 256, 0, stream>>>(out_w, out_wBh, out_wBl, 4 * 128 * 128);
    k_prepw_xp<<<(4 * 48 * 128 + 255) / 256, 256, 0, stream>>>(xp_w, xp_wBh, xp_wBl);
    k_a2<<<(4 * 128 * 16 + 255) / 256, 256, 0, stream>>>(A_log, A2, 4 * 128 * 16);
    k_init_h<<<NTOK * D / 256, 256, 0, stream>>>(x, inp_w, inp_b, h);

    for (int l = 0; l < 4; ++l) {
        k_ln_inproj_conv<<<NTOK / 32, 256, 0, stream>>>(
            h, ln_g + l * 128, ln_b + l * 128,
            in_wBh + l * 256 * 128, in_wBl + l * 256 * 128,
            xp_wBh + l * 48 * 128, xp_wBl + l * 48 * 128,
            conv_w + l * 128 * 3, conv_b + l * 128, xc, resy, bc, dlt);
        k_scan1<<<2048, 256, 0, stream>>>(xc, bc, dlt, dp_w + l * 128 * 8, dp_b + l * 128,
                                          A2 + l * 128 * 16, Pbuf, Fbuf);
        k_scan2<<<2048, 256, 0, stream>>>(xc, bc, dlt, dp_w + l * 128 * 8, dp_b + l * 128,
                                          A2 + l * 128 * 16, Dp + l * 128, Pbuf, Fbuf, resy);
        k_outproj<<<NTOK / 32, 256, 0, stream>>>(resy, out_wBh + l * 128 * 128,
                                                 out_wBl + l * 128 * 128, h);
    }
    k_final<<<NTOK / 4, 256, 0, stream>>>(h, outp_w, outp_b, (float*)d_out);
}

// Round 14
// 1521.103 us; speedup vs baseline: 1.0331x; 1.0036x over previous
//
#include <hip/hip_runtime.h>
#include <math.h>

#define D 128
#define NSTATE 16
#define DR 8
#define T_SEQ 1024
#define NTOK 131072  // 128 sequences * 1024 tokens
#define SEG 8        // segments per sequence (parallel scan)
#define SEGLEN 128   // T_SEQ / SEG
#define CH 16        // chunk (timesteps staged in LDS at once)
#define ZS 136       // bf16 elems per z row (128 + 8 pad -> 272B stride)
#define XRS2 132     // f32 elems per xr row (128 + 4 pad)

typedef __attribute__((ext_vector_type(8))) short bf16x8;
typedef __attribute__((ext_vector_type(4))) float f32x4;

#define LOG2E 1.44269504088896340736f
#define LN2   0.69314718055994530942f

// fast sigmoid: 1/(1+2^(-x*log2e)) via v_exp + v_rcp (~1 ulp)
__device__ __forceinline__ float sigmoidf_(float x) {
    return __builtin_amdgcn_rcpf(1.0f + exp2f(-x * LOG2E));
}
// fast softplus: ln2 * log2(1 + 2^(x*log2e)) via v_exp + v_log
__device__ __forceinline__ float softplusf_(float x) {
    float t = LN2 * __builtin_amdgcn_logf(1.0f + exp2f(x * LOG2E));
    return (x > 20.0f) ? x : t;
}
__device__ __forceinline__ short f2bf(float f) {   // RNE float->bf16
    union { float f; unsigned u; } v; v.f = f;
    unsigned r = v.u + 0x7FFFu + ((v.u >> 16) & 1u);
    return (short)(r >> 16);
}
__device__ __forceinline__ float bf2f(short s) {
    union { unsigned u; float f; } v; v.u = ((unsigned)(unsigned short)s) << 16;
    return v.f;
}

// ---------------- prep kernels ----------------

// f32 -> bf16 hi/lo split, elementwise (layout preserved)
__global__ void k_prepw(const float* __restrict__ src, short* __restrict__ hi,
                        short* __restrict__ lo, int n) {
    int i = blockIdx.x * 256 + threadIdx.x;
    if (i < n) {
        float f = src[i];
        short hh = f2bf(f);
        hi[i] = hh;
        lo[i] = f2bf(f - bf2f(hh));
    }
}

// xp_w (L,40,128) -> padded (L,48,128) bf16 hi/lo, rows 40..47 zero
__global__ void k_prepw_xp(const float* __restrict__ src, short* __restrict__ hi,
                           short* __restrict__ lo) {
    int i = blockIdx.x * 256 + threadIdx.x;     // over 4*48*128
    if (i >= 4 * 48 * 128) return;
    int l = i / (48 * 128);
    int rem = i - l * 48 * 128;
    int j = rem >> 7, k = rem & 127;
    float f = (j < 40) ? src[(l * 40 + j) * 128 + k] : 0.f;
    short hh = f2bf(f);
    hi[i] = hh;
    lo[i] = f2bf(f - bf2f(hh));
}

// A2 = -exp(A_log) * log2(e)
__global__ void k_a2(const float* __restrict__ A_log, float* __restrict__ A2, int total) {
    int idx = blockIdx.x * blockDim.x + threadIdx.x;
    if (idx < total) A2[idx] = -__expf(A_log[idx]) * LOG2E;
}

// h[tok][d] = x[tok] * inp_w[d] + inp_b[d]
__global__ void k_init_h(const float* __restrict__ x, const float* __restrict__ inp_w,
                         const float* __restrict__ inp_b, float* __restrict__ h) {
    int idx = blockIdx.x * blockDim.x + threadIdx.x;
    int tok = idx >> 7;
    int d = idx & 127;
    h[idx] = x[tok] * inp_w[d] + inp_b[d];
}

// ---------------- per-layer kernels ----------------
// Fused LN + in_proj (3-term split-bf16 MFMA) + causal conv(k=3) + SiLU
// + x_proj (second MFMA stage) -> xc, res, bc, dlt. Coalesced flush via LDS.
__global__ __launch_bounds__(256) void k_ln_inproj_conv(
    const float* __restrict__ h, const float* __restrict__ ln_g, const float* __restrict__ ln_b,
    const short* __restrict__ wh, const short* __restrict__ wl,   // in_proj (256,128) hi/lo
    const short* __restrict__ xph, const short* __restrict__ xpl, // x_proj padded (48,128) hi/lo
    const float* __restrict__ conv_w, const float* __restrict__ conv_b,
    float* __restrict__ xc, float* __restrict__ res,
    float* __restrict__ bc, float* __restrict__ dlt)
{
    __shared__ __align__(16) short zsh[48 * ZS];
    __shared__ __align__(16) short zsl[48 * ZS];
    __shared__ __align__(16) float xr[34 * XRS2];
    __shared__ __align__(16) float dbc_l[32][52];   // stage-2 out (40 used, 52 stride)
    const int tid = threadIdx.x;
    const int wv = tid >> 6, lane = tid & 63;
    const int tstart = blockIdx.x * 32;
    const int tin = tstart & (T_SEQ - 1);

    // Phase A: LayerNorm rows 0..33 -> bf16 hi/lo
    for (int r = wv; r < 34; r += 4) {
        int tr = tin + r - 2;
        if (tr < 0) {
            zsh[r * ZS + lane] = 0; zsh[r * ZS + lane + 64] = 0;
            zsl[r * ZS + lane] = 0; zsl[r * ZS + lane + 64] = 0;
            continue;
        }
        size_t row = (size_t)(tstart + r - 2) * D;
        float a = h[row + lane];
        float b = h[row + lane + 64];
        float s = a + b, ss = a * a + b * b;
        #pragma unroll
        for (int m = 1; m < 64; m <<= 1) { s += __shfl_xor(s, m); ss += __shfl_xor(ss, m); }
        float mu = s * (1.0f / 128.0f);
        float var = ss * (1.0f / 128.0f) - mu * mu;
        float rstd = rsqrtf(var + 1e-5f);
        float z0 = (a - mu) * rstd * ln_g[lane]      + ln_b[lane];
        float z1 = (b - mu) * rstd * ln_g[lane + 64] + ln_b[lane + 64];
        short h0 = f2bf(z0), h1 = f2bf(z1);
        zsh[r * ZS + lane]      = h0;
        zsh[r * ZS + lane + 64] = h1;
        zsl[r * ZS + lane]      = f2bf(z0 - bf2f(h0));
        zsl[r * ZS + lane + 64] = f2bf(z1 - bf2f(h1));
    }
    for (int i = tid; i < 14 * 128; i += 256) {
        int r = 34 + (i >> 7), c = i & 127;
        zsh[r * ZS + c] = 0;
        zsl[r * ZS + c] = 0;
    }

    // B panel (hi) -> registers
    const int colb = wv * 64 + (lane & 15);
    const int kb = (lane >> 4) * 8;
    bf16x8 bw[4][4];
    #pragma unroll
    for (int ct = 0; ct < 4; ++ct)
        #pragma unroll
        for (int kf = 0; kf < 4; ++kf)
            bw[ct][kf] = *(const bf16x8*)&wh[(colb + ct * 16) * 128 + kf * 32 + kb];
    __syncthreads();

    f32x4 acc[3][4];
    #pragma unroll
    for (int b = 0; b < 3; ++b)
        #pragma unroll
        for (int ct = 0; ct < 4; ++ct)
            acc[b][ct] = (f32x4){0.f, 0.f, 0.f, 0.f};

    // Pass 1: (a_hi + a_lo) * b_hi
    #pragma unroll
    for (int b = 0; b < 3; ++b) {
        bf16x8 ah[4], al[4];
        const int rbase = (b * 16 + (lane & 15)) * ZS + kb;
        #pragma unroll
        for (int kf = 0; kf < 4; ++kf) {
            ah[kf] = *(const bf16x8*)&zsh[rbase + kf * 32];
            al[kf] = *(const bf16x8*)&zsl[rbase + kf * 32];
        }
        #pragma unroll
        for (int ct = 0; ct < 4; ++ct)
            #pragma unroll
            for (int kf = 0; kf < 4; ++kf) {
                acc[b][ct] = __builtin_amdgcn_mfma_f32_16x16x32_bf16(ah[kf], bw[ct][kf], acc[b][ct], 0, 0, 0);
                acc[b][ct] = __builtin_amdgcn_mfma_f32_16x16x32_bf16(al[kf], bw[ct][kf], acc[b][ct], 0, 0, 0);
            }
    }
    // Pass 2: a_hi * b_lo
    #pragma unroll
    for (int ct = 0; ct < 4; ++ct)
        #pragma unroll
        for (int kf = 0; kf < 4; ++kf)
            bw[ct][kf] = *(const bf16x8*)&wl[(colb + ct * 16) * 128 + kf * 32 + kb];
    #pragma unroll
    for (int b = 0; b < 3; ++b) {
        bf16x8 ah[4];
        const int rbase = (b * 16 + (lane & 15)) * ZS + kb;
        #pragma unroll
        for (int kf = 0; kf < 4; ++kf)
            ah[kf] = *(const bf16x8*)&zsh[rbase + kf * 32];
        #pragma unroll
        for (int ct = 0; ct < 4; ++ct)
            #pragma unroll
            for (int kf = 0; kf < 4; ++kf)
                acc[b][ct] = __builtin_amdgcn_mfma_f32_16x16x32_bf16(ah[kf], bw[ct][kf], acc[b][ct], 0, 0, 0);
    }

    // conv-half acc (waves 0-1) -> xr; gate half stays in registers
    if (wv < 2) {
        #pragma unroll
        for (int b = 0; b < 3; ++b)
            #pragma unroll
            for (int ct = 0; ct < 4; ++ct) {
                const int col = wv * 64 + ct * 16 + (lane & 15);
                #pragma unroll
                for (int i = 0; i < 4; ++i) {
                    int row = b * 16 + ((lane >> 4) << 2) + i;
                    if (row < 34) xr[row * XRS2 + col] = acc[b][ct][i];
                }
            }
    }
    __syncthreads();

    // Epilogue: conv+silu, 256 threads (channel = tid&127, token half = tid>>7)
    {
        int ch = tid & 127, s0 = (tid >> 7) * 16;
        float c0 = conv_w[ch * 3 + 0], c1 = conv_w[ch * 3 + 1], c2 = conv_w[ch * 3 + 2];
        float cb = conv_b[ch];
        float v0 = xr[(s0 + 0) * XRS2 + ch], v1 = xr[(s0 + 1) * XRS2 + ch];
        #pragma unroll
        for (int s = 0; s < 16; ++s) {
            float v2 = xr[(s0 + s + 2) * XRS2 + ch];
            float v = v0 * c0 + v1 * c1 + v2 * c2 + cb;
            v = v * sigmoidf_(v);
            xc[(size_t)(tstart + s0 + s) * D + ch] = v;
            short hh = f2bf(v);
            zsh[(s0 + s) * ZS + ch] = hh;
            zsl[(s0 + s) * ZS + ch] = f2bf(v - bf2f(hh));
            v0 = v1; v1 = v2;
        }
    }
    __syncthreads();

    // gate-half acc (waves 2-3) -> xr rows 2..33 (xr conv columns free now);
    if (wv >= 2) {
        #pragma unroll
        for (int b = 0; b < 3; ++b)
            #pragma unroll
            for (int ct = 0; ct < 4; ++ct) {
                const int col = (wv - 2) * 64 + ct * 16 + (lane & 15);
                #pragma unroll
                for (int i = 0; i < 4; ++i) {
                    int row = b * 16 + ((lane >> 4) << 2) + i;
                    if (row >= 2 && row < 34) xr[row * XRS2 + col] = acc[b][ct][i];
                }
            }
    }
    // Stage 2 MFMA: dbc = xc @ xp_w.T (M=32, N=48 padded, K=128), 3-term split.
    for (int tile = wv; tile < 6; tile += 4) {
        const int b = tile & 1, ct = tile >> 1;
        const int jcol = ct * 16 + (lane & 15);
        const int rbase = (b * 16 + (lane & 15)) * ZS + kb;
        bf16x8 ah[4], al[4], bh[4];
        #pragma unroll
        for (int kf = 0; kf < 4; ++kf) {
            ah[kf] = *(const bf16x8*)&zsh[rbase + kf * 32];
            al[kf] = *(const bf16x8*)&zsl[rbase + kf * 32];
            bh[kf] = *(const bf16x8*)&xph[jcol * 128 + kf * 32 + kb];
        }
        f32x4 a2 = (f32x4){0.f, 0.f, 0.f, 0.f};
        #pragma unroll
        for (int kf = 0; kf < 4; ++kf) {
            a2 = __builtin_amdgcn_mfma_f32_16x16x32_bf16(ah[kf], bh[kf], a2, 0, 0, 0);
            a2 = __builtin_amdgcn_mfma_f32_16x16x32_bf16(al[kf], bh[kf], a2, 0, 0, 0);
        }
        #pragma unroll
        for (int kf = 0; kf < 4; ++kf) {
            bh[kf] = *(const bf16x8*)&xpl[jcol * 128 + kf * 32 + kb];
            a2 = __builtin_amdgcn_mfma_f32_16x16x32_bf16(ah[kf], bh[kf], a2, 0, 0, 0);
        }
        #pragma unroll
        for (int i = 0; i < 4; ++i) {
            int t = b * 16 + ((lane >> 4) << 2) + i;
            dbc_l[t][jcol] = a2[i];
        }
    }
    __syncthreads();

    // Coalesced flush: res (32 x 512B), bc (4KB contig), dlt (1KB contig)
    for (int fi = tid; fi < 1024; fi += 256) {
        int r = fi >> 5, c4 = fi & 31;
        *(float4*)&res[(size_t)(tstart + r) * D + c4 * 4] =
            *(const float4*)&xr[(r + 2) * XRS2 + c4 * 4];
    }
    {
        int t = tid >> 3, q = tid & 7;
        *(float4*)&bc[(size_t)(tstart + t) * 32 + q * 4] = *(const float4*)&dbc_l[t][8 + q * 4];
    }
    if (tid < 64) {
        int t = tid >> 1, j4 = tid & 1;
        *(float4*)&dlt[(size_t)(tstart + t) * 8 + j4 * 4] = *(const float4*)&dbc_l[t][j4 * 4];
    }
}

// ---- chunk-parallel selective scan ----
// Pass 1: per-segment scan from x=0 -> F, P. Grid 2048 x 256. B-half staging only.
__global__ __launch_bounds__(256) void k_scan1(
    const float* __restrict__ xc, const float* __restrict__ bc,
    const float* __restrict__ dlt,
    const float* __restrict__ dp_w, const float* __restrict__ dp_b,
    const float* __restrict__ A2,
    float* __restrict__ Pbuf, float* __restrict__ Fbuf)
{
    __shared__ float u_l[CH][64];
    __shared__ float du_l[CH][64];
    __shared__ float bc_l[CH][16];
    __shared__ float dlt_l[CH][8];
    __shared__ float dl_l[CH][64];
    __shared__ float dpw_s[64][9];
    __shared__ float dpb_s[64];

    const int tid = threadIdx.x;
    const int bt = blockIdx.x >> 4;
    const int seg = (blockIdx.x >> 1) & 7;
    const int d0 = (blockIdx.x & 1) * 64;
    const int dd = tid >> 2, q = tid & 3;
    const int d = d0 + dd;

    #pragma unroll
    for (int i = 0; i < 2; ++i) {
        int idx = tid + i * 256;
        dpw_s[idx >> 3][idx & 7] = dp_w[(d0 + (idx >> 3)) * 8 + (idx & 7)];
    }
    if (tid < 64) dpb_s[tid] = dp_b[d0 + tid];
    float A2q[4];
    #pragma unroll
    for (int jn = 0; jn < 4; ++jn) A2q[jn] = A2[d * NSTATE + q * 4 + jn];
    float x0 = 0.f, x1 = 0.f, x2 = 0.f, x3 = 0.f, S = 0.f;

    const size_t segbase = (size_t)bt * T_SEQ + (size_t)seg * SEGLEN;
    float4 su, sbc, sdl;
    su = *(const float4*)&xc[(segbase + (tid >> 4)) * D + d0 + (tid & 15) * 4];
    if (tid < 64)  sbc = *(const float4*)&bc[(segbase + (tid >> 2)) * 32 + (tid & 3) * 4];
    if (tid < 32)  sdl = *(const float4*)&dlt[(segbase + (tid >> 1)) * 8 + (tid & 1) * 4];

    for (int c = 0; c < SEGLEN / CH; ++c) {
        *(float4*)&u_l[tid >> 4][(tid & 15) * 4] = su;
        if (tid < 64)  *(float4*)&bc_l[tid >> 2][(tid & 3) * 4] = sbc;
        if (tid < 32)  *(float4*)&dlt_l[tid >> 1][(tid & 1) * 4] = sdl;
        __syncthreads();
        if (c + 1 < SEGLEN / CH) {
            const size_t nb = segbase + (size_t)(c + 1) * CH;
            su = *(const float4*)&xc[(nb + (tid >> 4)) * D + d0 + (tid & 15) * 4];
            if (tid < 64)  sbc = *(const float4*)&bc[(nb + (tid >> 2)) * 32 + (tid & 3) * 4];
            if (tid < 32)  sdl = *(const float4*)&dlt[(nb + (tid >> 1)) * 8 + (tid & 1) * 4];
        }
        {
            int col = tid & 63;
            #pragma unroll
            for (int i = 0; i < 4; ++i) {
                int row = (tid >> 6) + 4 * i;
                float v = dpb_s[col];
                #pragma unroll
                for (int r = 0; r < DR; ++r) v = fmaf(dlt_l[row][r], dpw_s[col][r], v);
                float dt = softplusf_(v);
                dl_l[row][col] = dt;
                du_l[row][col] = dt * u_l[row][col];
            }
        }
        __syncthreads();
        #pragma unroll
        for (int tl = 0; tl < CH; ++tl) {
            float dt = dl_l[tl][dd];
            float duv = du_l[tl][dd];
            S += dt;
            float4 Bq = *(const float4*)&bc_l[tl][q * 4];
            x0 = fmaf(exp2f(dt * A2q[0]), x0, duv * Bq.x);
            x1 = fmaf(exp2f(dt * A2q[1]), x1, duv * Bq.y);
            x2 = fmaf(exp2f(dt * A2q[2]), x2, duv * Bq.z);
            x3 = fmaf(exp2f(dt * A2q[3]), x3, duv * Bq.w);
        }
        __syncthreads();
    }
    const size_t o = ((size_t)(bt * SEG + seg) * D + d) * NSTATE + q * 4;
    *(float4*)&Fbuf[o] = make_float4(x0, x1, x2, x3);
    *(float4*)&Pbuf[o] = make_float4(exp2f(A2q[0] * S), exp2f(A2q[1] * S),
                                     exp2f(A2q[2] * S), exp2f(A2q[3] * S));
}

// Pass 2: inline fix-up then re-scan; y = C.x + u*Dp, gated, stored over res.
// Delta phase precomputes du = dt*u and uD = u*Dp once per (step,d); the
// hot loop is pure recurrence+dot; gating/store parallelized across q.
__global__ __launch_bounds__(256) void k_scan2(
    const float* __restrict__ xc, const float* __restrict__ bc,
    const float* __restrict__ dlt,
    const float* __restrict__ dp_w, const float* __restrict__ dp_b,
    const float* __restrict__ A2, const float* __restrict__ Dp,
    const float* __restrict__ Pbuf, const float* __restrict__ Fbuf,
    float* __restrict__ resy)
{
    __shared__ float u_l[CH][64];
    __shared__ float du_l[CH][64];
    __shared__ float uD_l[CH][64];
    __shared__ float r_l[CH][64];
    __shared__ float bc_l[CH][32];
    __shared__ float dlt_l[CH][8];
    __shared__ float dl_l[CH][64];
    __shared__ float dpw_s[64][9];
    __shared__ float dpb_s[64];

    const int tid = threadIdx.x;
    const int bt = blockIdx.x >> 4;
    const int seg = (blockIdx.x >> 1) & 7;
    const int d0 = (blockIdx.x & 1) * 64;
    const int dd = tid >> 2, q = tid & 3;
    const int d = d0 + dd;

    #pragma unroll
    for (int i = 0; i < 2; ++i) {
        int idx = tid + i * 256;
        dpw_s[idx >> 3][idx & 7] = dp_w[(d0 + (idx >> 3)) * 8 + (idx & 7)];
    }
    if (tid < 64) dpb_s[tid] = dp_b[d0 + tid];
    float A2q[4];
    #pragma unroll
    for (int jn = 0; jn < 4; ++jn) A2q[jn] = A2[d * NSTATE + q * 4 + jn];
    const float Dpc = Dp[d0 + (tid & 63)];   // for delta phase (col = tid&63)

    // inline fix-up: x_init = serial combine over segments 0..seg-1
    float x0 = 0.f, x1 = 0.f, x2 = 0.f, x3 = 0.f;
    for (int s = 0; s < seg; ++s) {
        const size_t idx = ((size_t)(bt * SEG + s) * D + d) * NSTATE + q * 4;
        float4 P = *(const float4*)&Pbuf[idx];
        float4 F = *(const float4*)&Fbuf[idx];
        x0 = fmaf(P.x, x0, F.x);
        x1 = fmaf(P.y, x1, F.y);
        x2 = fmaf(P.z, x2, F.z);
        x3 = fmaf(P.w, x3, F.w);
    }

    const size_t segbase = (size_t)bt * T_SEQ + (size_t)seg * SEGLEN;
    float4 su, sr, sbc, sdl;
    su = *(const float4*)&xc[(segbase + (tid >> 4)) * D + d0 + (tid & 15) * 4];
    sr = *(const float4*)&resy[(segbase + (tid >> 4)) * D + d0 + (tid & 15) * 4];
    if (tid < 128) sbc = *(const float4*)&bc[(segbase + (tid >> 3)) * 32 + (tid & 7) * 4];
    if (tid < 32)  sdl = *(const float4*)&dlt[(segbase + (tid >> 1)) * 8 + (tid & 1) * 4];

    for (int c = 0; c < SEGLEN / CH; ++c) {
        const size_t tb = segbase + (size_t)c * CH;
        *(float4*)&u_l[tid >> 4][(tid & 15) * 4] = su;
        *(float4*)&r_l[tid >> 4][(tid & 15) * 4] = sr;
        if (tid < 128) *(float4*)&bc_l[tid >> 3][(tid & 7) * 4] = sbc;
        if (tid < 32)  *(float4*)&dlt_l[tid >> 1][(tid & 1) * 4] = sdl;
        __syncthreads();
        if (c + 1 < SEGLEN / CH) {
            const size_t nb = tb + CH;
            su = *(const float4*)&xc[(nb + (tid >> 4)) * D + d0 + (tid & 15) * 4];
            sr = *(const float4*)&resy[(nb + (tid >> 4)) * D + d0 + (tid & 15) * 4];
            if (tid < 128) sbc = *(const float4*)&bc[(nb + (tid >> 3)) * 32 + (tid & 7) * 4];
            if (tid < 32)  sdl = *(const float4*)&dlt[(nb + (tid >> 1)) * 8 + (tid & 1) * 4];
        }
        // delta phase: dt, du = dt*u, uD = u*Dp (once per (step,d))
        {
            int col = tid & 63;
            #pragma unroll
            for (int i = 0; i < 4; ++i) {
                int row = (tid >> 6) + 4 * i;
                float v = dpb_s[col];
                #pragma unroll
                for (int r = 0; r < DR; ++r) v = fmaf(dlt_l[row][r], dpw_s[col][r], v);
                float dt = softplusf_(v);
                float uu = u_l[row][col];
                dl_l[row][col] = dt;
                du_l[row][col] = dt * uu;
                uD_l[row][col] = uu * Dpc;
            }
        }
        __syncthreads();
        float pacc[CH];
        #pragma unroll
        for (int tl = 0; tl < CH; ++tl) {
            float dt = dl_l[tl][dd];
            float duv = du_l[tl][dd];
            float4 Bq = *(const float4*)&bc_l[tl][q * 4];
            float4 Cq = *(const float4*)&bc_l[tl][16 + q * 4];
            x0 = fmaf(exp2f(dt * A2q[0]), x0, duv * Bq.x);
            x1 = fmaf(exp2f(dt * A2q[1]), x1, duv * Bq.y);
            x2 = fmaf(exp2f(dt * A2q[2]), x2, duv * Bq.z);
            x3 = fmaf(exp2f(dt * A2q[3]), x3, duv * Bq.w);
            float p = x0 * Cq.x;
            p = fmaf(x1, Cq.y, p);
            p = fmaf(x2, Cq.z, p);
            p = fmaf(x3, Cq.w, p);
            p += __shfl_xor(p, 1);
            p += __shfl_xor(p, 2);
            pacc[tl] = p;   // replicated across the 4 q-threads
        }
        // gating/store parallel across q: thread (dd,q) writes rows 4q..4q+3
        #pragma unroll
        for (int j = 0; j < 4; ++j) {
            int tl = q * 4 + j;
            float g = r_l[tl][dd];
            resy[(tb + tl) * D + d] = (pacc[tl] + uD_l[tl][dd]) * (g * sigmoidf_(g));
        }
        __syncthreads();
    }
}

// out_proj + residual via 3-term split-bf16 MFMA: h[t] += y[t] @ out_w.T
__global__ __launch_bounds__(256) void k_outproj(
    const float* __restrict__ y, const short* __restrict__ wh, const short* __restrict__ wl,
    float* __restrict__ h)
{
    __shared__ __align__(16) short ysh[32 * ZS];
    __shared__ __align__(16) short ysl[32 * ZS];
    const int tid = threadIdx.x;
    const int wv = tid >> 6, lane = tid & 63;
    const size_t tb = (size_t)blockIdx.x * 32;

    #pragma unroll
    for (int i = 0; i < 4; ++i) {
        int idx = tid + i * 256;
        int row = idx >> 5, c4 = idx & 31;
        float4 v = *(const float4*)&y[(tb + row) * D + c4 * 4];
        short h0 = f2bf(v.x), h1 = f2bf(v.y), h2 = f2bf(v.z), h3 = f2bf(v.w);
        *(short4*)&ysh[row * ZS + c4 * 4] = make_short4(h0, h1, h2, h3);
        *(short4*)&ysl[row * ZS + c4 * 4] = make_short4(
            f2bf(v.x - bf2f(h0)), f2bf(v.y - bf2f(h1)),
            f2bf(v.z - bf2f(h2)), f2bf(v.w - bf2f(h3)));
    }

    const int colb = wv * 32 + (lane & 15);
    const int kb = (lane >> 4) * 8;
    bf16x8 bw[2][4];
    #pragma unroll
    for (int ct = 0; ct < 2; ++ct)
        #pragma unroll
        for (int kf = 0; kf < 4; ++kf)
            bw[ct][kf] = *(const bf16x8*)&wh[(colb + ct * 16) * 128 + kf * 32 + kb];
    __syncthreads();

    f32x4 acc[2][2];
    #pragma unroll
    for (int b = 0; b < 2; ++b)
        #pragma unroll
        for (int ct = 0; ct < 2; ++ct)
            acc[b][ct] = (f32x4){0.f, 0.f, 0.f, 0.f};

    #pragma unroll
    for (int b = 0; b < 2; ++b) {
        bf16x8 ah[4], al[4];
        const int rbase = (b * 16 + (lane & 15)) * ZS + kb;
        #pragma unroll
        for (int kf = 0; kf < 4; ++kf) {
            ah[kf] = *(const bf16x8*)&ysh[rbase + kf * 32];
            al[kf] = *(const bf16x8*)&ysl[rbase + kf * 32];
        }
        #pragma unroll
        for (int ct = 0; ct < 2; ++ct)
            #pragma unroll
            for (int kf = 0; kf < 4; ++kf) {
                acc[b][ct] = __builtin_amdgcn_mfma_f32_16x16x32_bf16(ah[kf], bw[ct][kf], acc[b][ct], 0, 0, 0);
                acc[b][ct] = __builtin_amdgcn_mfma_f32_16x16x32_bf16(al[kf], bw[ct][kf], acc[b][ct], 0, 0, 0);
            }
    }
    #pragma unroll
    for (int ct = 0; ct < 2; ++ct)
        #pragma unroll
        for (int kf = 0; kf < 4; ++kf)
            bw[ct][kf] = *(const bf16x8*)&wl[(colb + ct * 16) * 128 + kf * 32 + kb];
    #pragma unroll
    for (int b = 0; b < 2; ++b) {
        bf16x8 ah[4];
        const int rbase = (b * 16 + (lane & 15)) * ZS + kb;
        #pragma unroll
        for (int kf = 0; kf < 4; ++kf)
            ah[kf] = *(const bf16x8*)&ysh[rbase + kf * 32];
        #pragma unroll
        for (int ct = 0; ct < 2; ++ct)
            #pragma unroll
            for (int kf = 0; kf < 4; ++kf)
                acc[b][ct] = __builtin_amdgcn_mfma_f32_16x16x32_bf16(ah[kf], bw[ct][kf], acc[b][ct], 0, 0, 0);
    }

    #pragma unroll
    for (int b = 0; b < 2; ++b)
        #pragma unroll
        for (int ct = 0; ct < 2; ++ct) {
            const int col = wv * 32 + ct * 16 + (lane & 15);
            #pragma unroll
            for (int i = 0; i < 4; ++i) {
                int row = b * 16 + ((lane >> 4) << 2) + i;
                size_t o = (tb + row) * D + col;
                h[o] += acc[b][ct][i];
            }
        }
}

// out[t] = h[t] . outp_w + outp_b  (one wave per token)
__global__ __launch_bounds__(256) void k_final(
    const float* __restrict__ h, const float* __restrict__ outp_w,
    const float* __restrict__ outp_b, float* __restrict__ out)
{
    const int tid = threadIdx.x;
    const int lane = tid & 63;
    const size_t tok = (size_t)blockIdx.x * 4 + (tid >> 6);
    float a = h[tok * D + lane] * outp_w[lane] + h[tok * D + lane + 64] * outp_w[lane + 64];
    #pragma unroll
    for (int m = 1; m < 64; m <<= 1) a += __shfl_xor(a, m);
    if (lane == 0) out[tok] = a + outp_b[0];
}

extern "C" void kernel_launch(void* const* d_in, const int* in_sizes, int n_in,
                              void* d_out, int out_size, void* d_ws, size_t ws_size,
                              hipStream_t stream)
{
    const float* x      = (const float*)d_in[0];
    const float* inp_w  = (const float*)d_in[1];
    const float* inp_b  = (const float*)d_in[2];
    const float* outp_w = (const float*)d_in[3];
    const float* outp_b = (const float*)d_in[4];
    const float* ln_g   = (const float*)d_in[5];
    const float* ln_b   = (const float*)d_in[6];
    const float* in_w   = (const float*)d_in[7];
    const float* conv_w = (const float*)d_in[8];
    const float* conv_b = (const float*)d_in[9];
    const float* xp_w   = (const float*)d_in[10];
    const float* dp_w   = (const float*)d_in[11];
    const float* dp_b   = (const float*)d_in[12];
    const float* A_log  = (const float*)d_in[13];
    const float* Dp     = (const float*)d_in[14];
    const float* out_w  = (const float*)d_in[15];

    float* ws = (float*)d_ws;
    size_t off = 0;
    float* h      = ws + off; off += (size_t)NTOK * D;
    float* xc     = ws + off; off += (size_t)NTOK * D;
    float* resy   = ws + off; off += (size_t)NTOK * D;
    float* bc     = ws + off; off += (size_t)NTOK * 32;
    float* dlt    = ws + off; off += (size_t)NTOK * 8;
    float* Pbuf   = ws + off; off += 128 * SEG * 2048;
    float* Fbuf   = ws + off; off += 128 * SEG * 2048;
    short* in_wBh = (short*)(ws + off); off += 4 * 256 * 128 / 2;
    short* in_wBl = (short*)(ws + off); off += 4 * 256 * 128 / 2;
    short* out_wBh= (short*)(ws + off); off += 4 * 128 * 128 / 2;
    short* out_wBl= (short*)(ws + off); off += 4 * 128 * 128 / 2;
    short* xp_wBh = (short*)(ws + off); off += 4 * 48 * 128 / 2;
    short* xp_wBl = (short*)(ws + off); off += 4 * 48 * 128 / 2;
    float* A2     = ws + off; off += 4 * 128 * 16;
    if (ws_size < off * sizeof(float)) return;  // workspace too small -> fail visibly

    // prep
    k_prepw<<<(4 * 256 * 128 + 255) / 256, 256, 0, stream>>>(in_w, in_wBh, in_wBl, 4 * 256 * 128);
    k_prepw<<<(4 * 128 * 128 + 255) / 256, 256, 0, stream>>>(out_w, out_wBh, out_wBl, 4 * 128 * 128);
    k_prepw_xp<<<(4 * 48 * 128 + 255) / 256, 256, 0, stream>>>(xp_w, xp_wBh, xp_wBl);
    k_a2<<<(4 * 128 * 16 + 255) / 256, 256, 0, stream>>>(A_log, A2, 4 * 128 * 16);
    k_init_h<<<NTOK * D / 256, 256, 0, stream>>>(x, inp_w, inp_b, h);

    for (int l = 0; l < 4; ++l) {
        k_ln_inproj_conv<<<NTOK / 32, 256, 0, stream>>>(
            h, ln_g + l * 128, ln_b + l * 128,
            in_wBh + l * 256 * 128, in_wBl + l * 256 * 128,
            xp_wBh + l * 48 * 128, xp_wBl + l * 48 * 128,
            conv_w + l * 128 * 3, conv_b + l * 128, xc, resy, bc, dlt);
        k_scan1<<<2048, 256, 0, stream>>>(xc, bc, dlt, dp_w + l * 128 * 8, dp_b + l * 128,
                                          A2 + l * 128 * 16, Pbuf, Fbuf);
        k_scan2<<<2048, 256, 0, stream>>>(xc, bc, dlt, dp_w + l * 128 * 8, dp_b + l * 128,
                                          A2 + l * 128 * 16, Dp + l * 128, Pbuf, Fbuf, resy);
        k_outproj<<<NTOK / 32, 256, 0, stream>>>(resy, out_wBh + l * 128 * 128,
                                                 out_wBl + l * 128 * 128, h);
    }
    k_final<<<NTOK / 4, 256, 0, stream>>>(h, outp_w, outp_b, (float*)d_out);
}